// Round 8
// baseline (3410.935 us; speedup 1.0000x reference)
//
#include <hip/hip_runtime.h>
#include <hip/hip_bf16.h>

// ---------------- workspace layout v8 (total 74,842,112 bytes) ----------------
// float indices into (float*)d_ws:
#define FC0_F   0        // fc0_w [64][3]
#define FC0B_F  192      // fc0_b [64]
#define PWF_F   256      // pw_w transposed [4][i][o] (16384)
#define PWB_F   16640    // pw_b [4][64]
#define FC1T_F  16896    // fc1_w transposed [64 i][128 f] (8192)
#define FC1B_F  25088    // fc1_b [128]
#define FC2_F   25216    // fc2_w [128]
#define FC2B_F  25344    // fc2_b [1]
#define PHW_F   25408    // phW [256 w][12 ky][2] (6144)
#define PHH_F   31552    // phH [256 x][24 kx][2] (12288) -> end 43840
#define FLAG_F  44032    // 1.0 => inputs f32
// bf16 element indices into (__hip_bfloat16*)d_ws:
#define HB_OFF_U  131072     // h [8][256][256][64]  (33554432 elems)
#define G_OFF_U   33685504   // G [8][256][64][12][2] (3145728 elems)
// float index for Fo:
#define FO_OFF_F  18415616   // Fo [8][12][24][64][2] f32 (294912)
#define WS_NEED   74842112
#define NTAB 43840

union FU8 { float f; unsigned u; };
__device__ __forceinline__ float bfu2f(unsigned short u) { FU8 v; v.u = ((unsigned)u) << 16; return v.f; }
__device__ __forceinline__ unsigned short f2bfu(float f) {
  FU8 v; v.f = f; unsigned b = v.u;
  return (unsigned short)((b + 0x7FFFu + ((b >> 16) & 1u)) >> 16);   // RNE
}
__device__ __forceinline__ float hunp8(const unsigned* hp, int i) {
  unsigned u = hp[i >> 1];
  return bfu2f((unsigned short)((i & 1) ? (u >> 16) : (u & 0xFFFFu)));
}
__device__ __forceinline__ unsigned pk2bf(float a, float b) {
  return (unsigned)f2bfu(a) | ((unsigned)f2bfu(b) << 16);
}
__device__ __forceinline__ float gelu8(float v) {
  return 0.5f * v * (1.0f + erff(v * 0.7071067811865475f));
}
__device__ __forceinline__ float rdw8(const __hip_bfloat16* h, const float* f,
                                      long i, int isf32) {
  return isf32 ? f[i] : __bfloat162float(h[i]);
}

// ---------------- fill output with a code (guards only) ----------------
__global__ __launch_bounds__(256) void kf8_fill(__hip_bfloat16* outH, float code) {
  outH[(size_t)blockIdx.x * 256 + threadIdx.x] = __float2bfloat16(code);
}

// ---------------- dtype detect on X ----------------
__global__ __launch_bounds__(64) void kd8_detect(const unsigned short* Xh, float* Wf) {
  if (threadIdx.x == 0 && blockIdx.x == 0) {
    int ok = 1;
    for (int k = 0; k < 128; ++k) {
      unsigned short u = Xh[2 * k];
      unsigned e = (u >> 7) & 0xFF;
      if (!(u == 0 || (e >= 0x60 && e <= 0x88))) ok = 0;
    }
    Wf[FLAG_F] = ok ? 0.0f : 1.0f;
  }
}

// ---------------- tables ----------------
__global__ __launch_bounds__(256) void kt8_tables(
    const __hip_bfloat16* f0h, const float* f0f,
    const __hip_bfloat16* f0bh, const float* f0bf,
    const __hip_bfloat16* pwh, const float* pwf,
    const __hip_bfloat16* pwbh, const float* pwbf,
    const __hip_bfloat16* f1h, const float* f1f,
    const __hip_bfloat16* f1bh, const float* f1bf,
    const __hip_bfloat16* f2h, const float* f2f,
    const __hip_bfloat16* f2bh, const float* f2bf,
    float* Wf) {
  const int isf32 = (Wf[FLAG_F] != 0.0f);
  const int stride = gridDim.x * blockDim.x;
  for (int n0 = blockIdx.x * blockDim.x + threadIdx.x; n0 < NTAB; n0 += stride) {
    int n = n0;
    if (n < 192) { Wf[FC0_F + n] = rdw8(f0h, f0f, n, isf32); continue; }
    n -= 192;
    if (n < 64)  { Wf[FC0B_F + n] = rdw8(f0bh, f0bf, n, isf32); continue; }
    n -= 64;
    if (n < 16384) { int l = n >> 12, i = (n >> 6) & 63, o = n & 63;
      Wf[PWF_F + n] = rdw8(pwh, pwf, (l*64 + o)*64 + i, isf32); continue; }
    n -= 16384;
    if (n < 256) { Wf[PWB_F + n] = rdw8(pwbh, pwbf, n, isf32); continue; }
    n -= 256;
    if (n < 8192) { int i = n >> 7, f = n & 127;
      Wf[FC1T_F + n] = rdw8(f1h, f1f, f*64 + i, isf32); continue; }
    n -= 8192;
    if (n < 128) { Wf[FC1B_F + n] = rdw8(f1bh, f1bf, n, isf32); continue; }
    n -= 128;
    if (n < 128) { Wf[FC2_F + n] = rdw8(f2h, f2f, n, isf32); continue; }
    n -= 128;
    if (n < 1)   { Wf[FC2B_F + n] = rdw8(f2bh, f2bf, 0, isf32); continue; }
    n -= 1;
    if (n < 6144) { int w = n / 24, r = n % 24, ky = r >> 1, part = r & 1;
      int idx = (w * ky) & 255; float a = idx * (1.0f/128.0f);
      Wf[PHW_F + n] = part ? sinpif(a) : cospif(a); continue; }
    n -= 6144;
    { int x = n / 48, r = n % 48, kx = r >> 1, part = r & 1;
      int kxa = (kx < 12) ? kx : kx + 232;          // 244..255 = negative H rows
      int idx = (x * kxa) & 255; float a = idx * (1.0f/128.0f);
      Wf[PHH_F + n] = part ? sinpif(a) : cospif(a); }
  }
}

// hrow32 packed-pair swizzled image of the (b,x) row:
//   word for (pixel p, channel-pair cp) at hrow32[cp*256 + ((p + 2*cp) & 255)]
// ---------------- forward DFT along W of the LDS row -> G ----------------
__device__ void gstep8(const float* Wf, __hip_bfloat16* G,
                       unsigned* hrow32, float* pbuf, int b, int x) {
  const int t = threadIdx.x;
  const int c = t & 63, q = t >> 6;
  const int cp = c >> 1, hi = c & 1;
  float aR[12], aI[12];
#pragma unroll
  for (int k = 0; k < 12; ++k) { aR[k] = 0.0f; aI[k] = 0.0f; }
  for (int j = 0; j < 64; ++j) {
    int w = q*64 + j;                            // wave-uniform
    unsigned u = hrow32[cp*256 + ((w + 2*cp) & 255)];
    float hv = bfu2f((unsigned short)(hi ? (u >> 16) : (u & 0xFFFFu)));
    const float* ph = Wf + PHW_F + w*24;
#pragma unroll
    for (int k = 0; k < 12; ++k) {
      aR[k] += hv * ph[2*k];
      aI[k] -= hv * ph[2*k + 1];
    }
  }
  __syncthreads();                               // all hrow reads done; pbuf may overwrite
#pragma unroll
  for (int k = 0; k < 12; ++k) {
    pbuf[q*1600 + c*25 + 2*k]     = aR[k];
    pbuf[q*1600 + c*25 + 2*k + 1] = aI[k];
  }
  __syncthreads();
  unsigned* Grow = (unsigned*)((unsigned short*)G + (size_t)(b*256 + x)*1536);
#pragma unroll
  for (int j = 0; j < 3; ++j) {
    int p = j*256 + t;                 // pair index; elem 2p = cc*24 + m
    int cc = p / 12;
    int m0 = 2*p - cc*24;
    float s0 = pbuf[cc*25 + m0]     + pbuf[1600 + cc*25 + m0]
             + pbuf[3200 + cc*25 + m0]     + pbuf[4800 + cc*25 + m0];
    float s1 = pbuf[cc*25 + m0 + 1] + pbuf[1600 + cc*25 + m0 + 1]
             + pbuf[3200 + cc*25 + m0 + 1] + pbuf[4800 + cc*25 + m0 + 1];
    Grow[p] = pk2bf(s0, s1);
  }
}

// coalesced HB(row) -> LDS image
__device__ __forceinline__ void row_load(const __hip_bfloat16* HB, unsigned* hrow32,
                                         int b, int x, uint4* st) {
  const uint4* hbR = (const uint4*)(HB + (size_t)(b*256 + x)*16384);
  const int t = threadIdx.x;
#pragma unroll
  for (int j = 0; j < 8; ++j) st[j] = hbR[j*256 + t];
}
__device__ __forceinline__ void row_stage(unsigned* hrow32, const uint4* st) {
  const int t = threadIdx.x;
#pragma unroll
  for (int j = 0; j < 8; ++j) {
    int n = j*256 + t, p = n >> 3, cg = n & 7;
    unsigned vv[4] = {st[j].x, st[j].y, st[j].z, st[j].w};
#pragma unroll
    for (int m = 0; m < 4; ++m) {
      int cp = cg*4 + m;
      hrow32[cp*256 + ((p + 2*cp) & 255)] = vv[m];
    }
  }
}
// coalesced LDS image -> HB(row)
__device__ __forceinline__ void row_store(__hip_bfloat16* HB, const unsigned* hrow32,
                                          int b, int x) {
  uint4* hbW = (uint4*)(HB + (size_t)(b*256 + x)*16384);
  const int t = threadIdx.x;
#pragma unroll
  for (int j = 0; j < 8; ++j) {
    int n = j*256 + t, p = n >> 3, cg = n & 7;
    unsigned vv[4];
#pragma unroll
    for (int m = 0; m < 4; ++m) {
      int cp = cg*4 + m;
      vv[m] = hrow32[cp*256 + ((p + 2*cp) & 255)];
    }
    hbW[n] = make_uint4(vv[0], vv[1], vv[2], vv[3]);
  }
}

// ---------------- lift: fc0 -> LDS image -> HB (coalesced), DFT-W -> G ----------------
__global__ __launch_bounds__(256) void kl8_lift(const __hip_bfloat16* Xh, const float* Xf,
                                                const float* Wf,
                                                __hip_bfloat16* HB, __hip_bfloat16* G) {
  __shared__ __align__(16) char smem[32768];
  unsigned* hrow32 = (unsigned*)smem;
  float* pbuf = (float*)smem;
  const int b = blockIdx.x >> 8, x = blockIdx.x & 255;
  const int w = threadIdx.x;
  const int isf32 = (Wf[FLAG_F] != 0.0f);
  float xv = isf32 ? Xf[(size_t)(b*256 + x)*256 + w]
                   : __bfloat162float(Xh[(size_t)(b*256 + x)*256 + w]);
  float gx = x * (1.0f/255.0f), gy = w * (1.0f/255.0f);
#pragma unroll
  for (int cp = 0; cp < 32; ++cp) {
    int c = cp*2;
    float h0 = xv*Wf[FC0_F + c*3]     + gx*Wf[FC0_F + c*3 + 1]
             + gy*Wf[FC0_F + c*3 + 2] + Wf[FC0B_F + c];
    float h1 = xv*Wf[FC0_F + c*3 + 3] + gx*Wf[FC0_F + c*3 + 4]
             + gy*Wf[FC0_F + c*3 + 5] + Wf[FC0B_F + c + 1];
    hrow32[cp*256 + ((w + 2*cp) & 255)] = pk2bf(h0, h1);
  }
  __syncthreads();
  row_store(HB, hrow32, b, x);
  gstep8(Wf, G, hrow32, pbuf, b, x);
}

// ---------------- spectral: block=(b,kx); DFT-H + channel mix -> Fo ----------------
__global__ __launch_bounds__(256) void ks8_spec(const float* Wf, const __hip_bfloat16* G,
    const __hip_bfloat16* w1h, const float* w1f,
    const __hip_bfloat16* w2h, const float* w2f,
    float* Fo, int l) {
  __shared__ float pbufA[6400];
  __shared__ float Fbuf[1536];     // F [i][24] (ky pairs)
  const int b = blockIdx.x / 24, kx = blockIdx.x % 24;
  const int t = threadIdx.x;
  const int isf32 = (Wf[FLAG_F] != 0.0f);
  // A: F[i][ky] = sum_x G[b][x][i][ky] * e^{-i 2pi x kxa/256}
  {
    const int i = t & 63, q = t >> 6;
    float fr[12], fi[12];
#pragma unroll
    for (int k = 0; k < 12; ++k) { fr[k] = 0.0f; fi[k] = 0.0f; }
    for (int j = 0; j < 64; ++j) {
      int x = q*64 + j;                          // wave-uniform
      const uint4* gp = (const uint4*)((const unsigned short*)G
                        + (size_t)(b*256 + x)*1536 + i*24);
      uint4 u0 = gp[0], u1 = gp[1], u2 = gp[2];
      float cc = Wf[PHH_F + x*48 + 2*kx], ss = Wf[PHH_F + x*48 + 2*kx + 1];
      unsigned uu[12] = {u0.x, u0.y, u0.z, u0.w, u1.x, u1.y, u1.z, u1.w,
                         u2.x, u2.y, u2.z, u2.w};
#pragma unroll
      for (int k = 0; k < 12; ++k) {
        float gr = bfu2f((unsigned short)(uu[k] & 0xFFFFu));
        float gi = bfu2f((unsigned short)(uu[k] >> 16));
        fr[k] += gr*cc + gi*ss;
        fi[k] += gi*cc - gr*ss;
      }
    }
#pragma unroll
    for (int k = 0; k < 12; ++k) {
      pbufA[q*1600 + i*25 + 2*k]     = fr[k];
      pbufA[q*1600 + i*25 + 2*k + 1] = fi[k];
    }
  }
  __syncthreads();
#pragma unroll
  for (int j = 0; j < 6; ++j) {
    int idx = j*256 + t;                         // 1536 = i*24 + m
    int cc = idx / 24, m = idx - cc*24;
    Fbuf[idx] = pbufA[cc*25 + m] + pbufA[1600 + cc*25 + m]
              + pbufA[3200 + cc*25 + m] + pbufA[4800 + cc*25 + m];
  }
  __syncthreads();
  // B: Fo[ky][o] = sum_i F[i][ky] * W[l][i][o][kx][ky]
  {
    const int o = t & 63, q = t >> 6;
    float br[12], bi[12];
#pragma unroll
    for (int k = 0; k < 12; ++k) { br[k] = 0.0f; bi[k] = 0.0f; }
    const int kxe = (kx < 12) ? kx : kx - 12;
    const __hip_bfloat16* wh = (kx < 12) ? w1h : w2h;
    const float*         wfp = (kx < 12) ? w1f : w2f;
    for (int i = q*16; i < q*16 + 16; ++i) {
      size_t widx = ((size_t)((l*64 + i)*64 + o))*288 + (size_t)kxe*24;
      float wr_[12], wi_[12];
      if (isf32) {
        const float* wp = wfp + widx;
#pragma unroll
        for (int k = 0; k < 12; ++k) { wr_[k] = wp[2*k]; wi_[k] = wp[2*k + 1]; }
      } else {
        const uint4* wp = (const uint4*)((const unsigned short*)wh + widx);
        uint4 u0 = wp[0], u1 = wp[1], u2 = wp[2];
        unsigned uu[12] = {u0.x, u0.y, u0.z, u0.w, u1.x, u1.y, u1.z, u1.w,
                           u2.x, u2.y, u2.z, u2.w};
#pragma unroll
        for (int k = 0; k < 12; ++k) {
          wr_[k] = bfu2f((unsigned short)(uu[k] & 0xFFFFu));
          wi_[k] = bfu2f((unsigned short)(uu[k] >> 16));
        }
      }
      const float* Fp = Fbuf + i*24;
#pragma unroll
      for (int k = 0; k < 12; ++k) {
        float Fr = Fp[2*k], Fi = Fp[2*k + 1];
        br[k] += Fr*wr_[k] - Fi*wi_[k];
        bi[k] += Fr*wi_[k] + Fi*wr_[k];
      }
    }
#pragma unroll
    for (int k = 0; k < 12; ++k) {
      pbufA[q*1536 + k*128 + o*2]     = br[k];
      pbufA[q*1536 + k*128 + o*2 + 1] = bi[k];
    }
  }
  __syncthreads();
#pragma unroll
  for (int j = 0; j < 6; ++j) {
    int n = j*256 + t;                           // 1536 = ky*128 + o*2 + p
    int ky = n >> 7, r = n & 127;
    Fo[((size_t)(b*12 + ky)*24 + kx)*128 + r] =
        pbufA[n] + pbufA[1536 + n] + pbufA[3072 + n] + pbufA[4608 + n];
  }
}

// ---------------- layer: inv-H + inv-W + pointwise + GELU (+ next DFT-W) ----------------
__global__ __launch_bounds__(256, 4) void ky8_layer(const float* Wf,
                                                    __hip_bfloat16* HB,
                                                    __hip_bfloat16* G,
                                                    const float* Fo,
                                                    int l, int last) {
  __shared__ __align__(16) char smem[38912];     // hrow32 32KB (alias pbuf) + gbuf 6KB
  unsigned* hrow32 = (unsigned*)smem;
  float* pbuf = (float*)smem;
  float* gbuf = (float*)(smem + 32768);          // [ky][o][2] 1536 floats
  const int b = blockIdx.x >> 8, x = blockIdx.x & 255;
  const int t = threadIdx.x;
  // A1: issue coalesced row loads
  uint4 st[8];
  row_load(HB, hrow32, b, x, st);
  // A2: gbuf (inv-H) while loads are in flight
  {
    const float2* FoG = (const float2*)(Fo + (size_t)b*12*24*128);
    const float* phx = Wf + PHH_F + x*48;
#pragma unroll
    for (int j = 0; j < 3; ++j) {
      int e = j*256 + t;                         // 768 = ky*64 + o
      int o = e & 63, ky = e >> 6;
      float gr = 0.0f, gi = 0.0f;
#pragma unroll
      for (int kx = 0; kx < 24; ++kx) {
        float cc = phx[2*kx], ss = phx[2*kx + 1];
        float2 f = FoG[(ky*24 + kx)*64 + o];
        gr += f.x*cc - f.y*ss;
        gi += f.x*ss + f.y*cc;
      }
      gbuf[ky*128 + o*2]     = gr;
      gbuf[ky*128 + o*2 + 1] = gi;
    }
  }
  // A3: stage row into LDS image
  row_stage(hrow32, st);
  __syncthreads();
  // B: per-pixel compute (thread t owns pixel w = t; only owner touches its words)
  const int w = t;
  unsigned hp[32];
#pragma unroll
  for (int cp = 0; cp < 32; ++cp) hp[cp] = hrow32[cp*256 + ((w + 2*cp) & 255)];
  float pc[11], ps[11];
#pragma unroll
  for (int k = 0; k < 11; ++k) {
    int idx = (w*(k + 1)) & 255;
    float a = idx * (1.0f/128.0f);
    pc[k] = 2.0f * cospif(a);
    ps[k] = 2.0f * sinpif(a);
  }
  const float* pw  = Wf + PWF_F + l*4096;
  const float* pwb = Wf + PWB_F + l*64;
#pragma unroll 1
  for (int half = 0; half < 2; ++half) {
    const int o0 = half*32;
    float acc[32];
#pragma unroll
    for (int oo = 0; oo < 32; ++oo) acc[oo] = gbuf[(o0 + oo)*2];
#pragma unroll
    for (int k = 1; k < 12; ++k) {
#pragma unroll
      for (int oo = 0; oo < 32; ++oo)
        acc[oo] += gbuf[k*128 + (o0 + oo)*2] * pc[k-1]
                 - gbuf[k*128 + (o0 + oo)*2 + 1] * ps[k-1];
    }
#pragma unroll
    for (int oo = 0; oo < 32; ++oo) acc[oo] = pwb[o0 + oo] + acc[oo] * (1.0f/65536.0f);
    for (int i = 0; i < 64; ++i) {
      float hv = hunp8(hp, i);
#pragma unroll
      for (int oo = 0; oo < 32; ++oo) acc[oo] += hv * pw[i*64 + o0 + oo];
    }
#pragma unroll
    for (int m = 0; m < 16; ++m) {
      int oo = m*2;
      float v0 = acc[oo], v1 = acc[oo + 1];
      if (!last) { v0 = gelu8(v0); v1 = gelu8(v1); }
      int cp = half*16 + m;
      hrow32[cp*256 + ((w + 2*cp) & 255)] = pk2bf(v0, v1);
    }
  }
  __syncthreads();
  // C: coalesced store of the new row
  row_store(HB, hrow32, b, x);
  // D: forward DFT-W for next layer
  if (!last) gstep8(Wf, G, hrow32, pbuf, b, x);
}

// ---------------- head: fc1 + GELU + fc2 -> out ----------------
__global__ __launch_bounds__(256, 4) void kh8_head(const float* Wf,
                                                   const __hip_bfloat16* HB,
                                                   __hip_bfloat16* outH, float* outF) {
  __shared__ __align__(16) char smem[32768];
  unsigned* hrow32 = (unsigned*)smem;
  const int b = blockIdx.x >> 8, x = blockIdx.x & 255;
  const int t = threadIdx.x;
  const int w = t;
  const int isf32 = (Wf[FLAG_F] != 0.0f);
  uint4 st[8];
  row_load(HB, hrow32, b, x, st);
  row_stage(hrow32, st);
  __syncthreads();
  unsigned hp[32];
#pragma unroll
  for (int cp = 0; cp < 32; ++cp) hp[cp] = hrow32[cp*256 + ((w + 2*cp) & 255)];
  float total = Wf[FC2B_F];
#pragma unroll 1
  for (int half = 0; half < 2; ++half) {
    float acc[64];
#pragma unroll
    for (int o = 0; o < 64; ++o) acc[o] = Wf[FC1B_F + half*64 + o];
    for (int i = 0; i < 64; ++i) {
      float hv = hunp8(hp, i);
#pragma unroll
      for (int o = 0; o < 64; ++o) acc[o] += hv * Wf[FC1T_F + i*128 + half*64 + o];
    }
#pragma unroll
    for (int o = 0; o < 64; ++o)
      total += gelu8(acc[o]) * Wf[FC2_F + half*64 + o];
  }
  size_t idx = (size_t)(b*256 + x)*256 + w;
  if (isf32) outF[idx] = total;
  else       outH[idx] = __float2bfloat16(total);
}

// ---------------- launcher ----------------
extern "C" void kernel_launch(void* const* d_in, const int* in_sizes, int n_in,
                              void* d_out, int out_size, void* d_ws, size_t ws_size,
                              hipStream_t stream) {
  (void)out_size;
  __hip_bfloat16* outH = (__hip_bfloat16*)d_out;
  float*          outF = (float*)d_out;
  float*          Wf   = (float*)d_ws;
  __hip_bfloat16* HB   = (__hip_bfloat16*)d_ws + HB_OFF_U;
  __hip_bfloat16* G    = (__hip_bfloat16*)d_ws + G_OFF_U;
  float*          Fo   = (float*)d_ws + FO_OFF_F;

  static const int EXP_SZ[11] = {524288, 192, 64, 4718592, 4718592,
                                 16384, 256, 8192, 128, 128, 1};
  if (n_in != 11) { kf8_fill<<<2048, 256, 0, stream>>>(outH, 27648.0f); return; }
  for (int i = 0; i < 11; ++i) {
    if (in_sizes[i] != EXP_SZ[i]) {
      kf8_fill<<<2048, 256, 0, stream>>>(outH, 28672.0f + 256.0f * (float)i);
      return;
    }
  }
  if (ws_size < (size_t)WS_NEED) {
    int q = (int)(ws_size >> 25); if (q > 31) q = 31;
    kf8_fill<<<2048, 256, 0, stream>>>(outH, 4096.0f + 32.0f * (float)q);
    return;
  }

  kd8_detect<<<1, 64, 0, stream>>>((const unsigned short*)d_in[0], Wf);
  kt8_tables<<<64, 256, 0, stream>>>(
      (const __hip_bfloat16*)d_in[1], (const float*)d_in[1],
      (const __hip_bfloat16*)d_in[2], (const float*)d_in[2],
      (const __hip_bfloat16*)d_in[5], (const float*)d_in[5],
      (const __hip_bfloat16*)d_in[6], (const float*)d_in[6],
      (const __hip_bfloat16*)d_in[7], (const float*)d_in[7],
      (const __hip_bfloat16*)d_in[8], (const float*)d_in[8],
      (const __hip_bfloat16*)d_in[9], (const float*)d_in[9],
      (const __hip_bfloat16*)d_in[10], (const float*)d_in[10],
      Wf);
  kl8_lift<<<2048, 256, 0, stream>>>((const __hip_bfloat16*)d_in[0],
                                     (const float*)d_in[0], Wf, HB, G);
  for (int l = 0; l < 4; ++l) {
    ks8_spec<<<192, 256, 0, stream>>>(Wf, G,
        (const __hip_bfloat16*)d_in[3], (const float*)d_in[3],
        (const __hip_bfloat16*)d_in[4], (const float*)d_in[4],
        Fo, l);
    ky8_layer<<<2048, 256, 0, stream>>>(Wf, HB, G, Fo, l, (l == 3) ? 1 : 0);
  }
  kh8_head<<<2048, 256, 0, stream>>>(Wf, HB, outH, outF);
}

// Round 9
// 3368.526 us; speedup vs baseline: 1.0126x; 1.0126x over previous
//
#include <hip/hip_runtime.h>
#include <hip/hip_bf16.h>

// ---------------- workspace layout v9 (total 74,842,112 bytes) ----------------
// float indices into (float*)d_ws:
#define FC0_F   0        // fc0_w [64][3]
#define FC0B_F  192      // fc0_b [64]
#define PWF_F   256      // pw_w transposed [4][i][o] (16384)
#define PWB_F   16640    // pw_b [4][64]
#define FC1T_F  16896    // fc1_w transposed [64 i][128 f] (8192)
#define FC1B_F  25088    // fc1_b [128]
#define FC2_F   25216    // fc2_w [128]
#define FC2B_F  25344    // fc2_b [1]
#define PHW_F   25408    // phW [256 w][12 ky][2] (6144)
#define PHH_F   31552    // phH [256 x][24 kx][2] (12288) -> end 43840
#define FLAG_F  44032    // 1.0 => inputs f32
// bf16 element indices into (__hip_bfloat16*)d_ws:
#define HB_OFF_U  131072     // h [8][256][256][64]  (33554432 elems)
#define GG_OFF_U  33685504   // G / g2 shared region: [8][256] rows x 1536 bf16
// float index for Fo:
#define FO_OFF_F  18415616   // Fo [8][12][24][64][2] f32 (294912)
#define WS_NEED   74842112
#define NTAB 43840

union FU9 { float f; unsigned u; };
__device__ __forceinline__ float bfu2f(unsigned short u) { FU9 v; v.u = ((unsigned)u) << 16; return v.f; }
__device__ __forceinline__ unsigned short f2bfu(float f) {
  FU9 v; v.f = f; unsigned b = v.u;
  return (unsigned short)((b + 0x7FFFu + ((b >> 16) & 1u)) >> 16);   // RNE
}
__device__ __forceinline__ float hunp9(const unsigned* hp, int i) {
  unsigned u = hp[i >> 1];
  return bfu2f((unsigned short)((i & 1) ? (u >> 16) : (u & 0xFFFFu)));
}
__device__ __forceinline__ unsigned pk2bf(float a, float b) {
  return (unsigned)f2bfu(a) | ((unsigned)f2bfu(b) << 16);
}
__device__ __forceinline__ float gelu9(float v) {
  return 0.5f * v * (1.0f + erff(v * 0.7071067811865475f));
}
__device__ __forceinline__ float rdw9(const __hip_bfloat16* h, const float* f,
                                      long i, int isf32) {
  return isf32 ? f[i] : __bfloat162float(h[i]);
}

// ---------------- fill output with a code (guards only) ----------------
__global__ __launch_bounds__(256) void kf9_fill(__hip_bfloat16* outH, float code) {
  outH[(size_t)blockIdx.x * 256 + threadIdx.x] = __float2bfloat16(code);
}

// ---------------- dtype detect on X ----------------
__global__ __launch_bounds__(64) void kd9_detect(const unsigned short* Xh, float* Wf) {
  if (threadIdx.x == 0 && blockIdx.x == 0) {
    int ok = 1;
    for (int k = 0; k < 128; ++k) {
      unsigned short u = Xh[2 * k];
      unsigned e = (u >> 7) & 0xFF;
      if (!(u == 0 || (e >= 0x60 && e <= 0x88))) ok = 0;
    }
    Wf[FLAG_F] = ok ? 0.0f : 1.0f;
  }
}

// ---------------- tables ----------------
__global__ __launch_bounds__(256) void kt9_tables(
    const __hip_bfloat16* f0h, const float* f0f,
    const __hip_bfloat16* f0bh, const float* f0bf,
    const __hip_bfloat16* pwh, const float* pwf,
    const __hip_bfloat16* pwbh, const float* pwbf,
    const __hip_bfloat16* f1h, const float* f1f,
    const __hip_bfloat16* f1bh, const float* f1bf,
    const __hip_bfloat16* f2h, const float* f2f,
    const __hip_bfloat16* f2bh, const float* f2bf,
    float* Wf) {
  const int isf32 = (Wf[FLAG_F] != 0.0f);
  const int stride = gridDim.x * blockDim.x;
  for (int n0 = blockIdx.x * blockDim.x + threadIdx.x; n0 < NTAB; n0 += stride) {
    int n = n0;
    if (n < 192) { Wf[FC0_F + n] = rdw9(f0h, f0f, n, isf32); continue; }
    n -= 192;
    if (n < 64)  { Wf[FC0B_F + n] = rdw9(f0bh, f0bf, n, isf32); continue; }
    n -= 64;
    if (n < 16384) { int l = n >> 12, i = (n >> 6) & 63, o = n & 63;
      Wf[PWF_F + n] = rdw9(pwh, pwf, (l*64 + o)*64 + i, isf32); continue; }
    n -= 16384;
    if (n < 256) { Wf[PWB_F + n] = rdw9(pwbh, pwbf, n, isf32); continue; }
    n -= 256;
    if (n < 8192) { int i = n >> 7, f = n & 127;
      Wf[FC1T_F + n] = rdw9(f1h, f1f, f*64 + i, isf32); continue; }
    n -= 8192;
    if (n < 128) { Wf[FC1B_F + n] = rdw9(f1bh, f1bf, n, isf32); continue; }
    n -= 128;
    if (n < 128) { Wf[FC2_F + n] = rdw9(f2h, f2f, n, isf32); continue; }
    n -= 128;
    if (n < 1)   { Wf[FC2B_F + n] = rdw9(f2bh, f2bf, 0, isf32); continue; }
    n -= 1;
    if (n < 6144) { int w = n / 24, r = n % 24, ky = r >> 1, part = r & 1;
      int idx = (w * ky) & 255; float a = idx * (1.0f/128.0f);
      Wf[PHW_F + n] = part ? sinpif(a) : cospif(a); continue; }
    n -= 6144;
    { int x = n / 48, r = n % 48, kx = r >> 1, part = r & 1;
      int kxa = (kx < 12) ? kx : kx + 232;          // 244..255 = negative H rows
      int idx = (x * kxa) & 255; float a = idx * (1.0f/128.0f);
      Wf[PHH_F + n] = part ? sinpif(a) : cospif(a); }
  }
}

// hrow32 packed-pair swizzled image of the (b,x) row:
//   word for (pixel p, channel-pair cp) at hrow32[cp*256 + ((p + 2*cp) & 255)]
// ---------------- forward DFT along W of the LDS row -> G rows in GG ----------------
__device__ void gstep9(const float* Wf, __hip_bfloat16* GG,
                       unsigned* hrow32, float* pbuf, int b, int x) {
  const int t = threadIdx.x;
  const int c = t & 63, q = t >> 6;
  const int cp = c >> 1, hi = c & 1;
  float aR[12], aI[12];
#pragma unroll
  for (int k = 0; k < 12; ++k) { aR[k] = 0.0f; aI[k] = 0.0f; }
  for (int j = 0; j < 64; ++j) {
    int w = q*64 + j;                            // wave-uniform
    unsigned u = hrow32[cp*256 + ((w + 2*cp) & 255)];
    float hv = bfu2f((unsigned short)(hi ? (u >> 16) : (u & 0xFFFFu)));
    const float* ph = Wf + PHW_F + w*24;
#pragma unroll
    for (int k = 0; k < 12; ++k) {
      aR[k] += hv * ph[2*k];
      aI[k] -= hv * ph[2*k + 1];
    }
  }
  __syncthreads();                               // hrow reads done; pbuf may overwrite
#pragma unroll
  for (int k = 0; k < 12; ++k) {
    pbuf[q*1600 + c*25 + 2*k]     = aR[k];
    pbuf[q*1600 + c*25 + 2*k + 1] = aI[k];
  }
  __syncthreads();
  unsigned* Grow = (unsigned*)((unsigned short*)GG + (size_t)(b*256 + x)*1536);
#pragma unroll
  for (int j = 0; j < 3; ++j) {
    int p = j*256 + t;                 // pair index; elem 2p = cc*24 + m  ([i][ky][2] row)
    int cc = p / 12;
    int m0 = 2*p - cc*24;
    float s0 = pbuf[cc*25 + m0]     + pbuf[1600 + cc*25 + m0]
             + pbuf[3200 + cc*25 + m0]     + pbuf[4800 + cc*25 + m0];
    float s1 = pbuf[cc*25 + m0 + 1] + pbuf[1600 + cc*25 + m0 + 1]
             + pbuf[3200 + cc*25 + m0 + 1] + pbuf[4800 + cc*25 + m0 + 1];
    Grow[p] = pk2bf(s0, s1);
  }
}

// coalesced LDS image -> HB(row)
__device__ __forceinline__ void row_store9(__hip_bfloat16* HB, const unsigned* hrow32,
                                           int b, int x) {
  uint4* hbW = (uint4*)(HB + (size_t)(b*256 + x)*16384);
  const int t = threadIdx.x;
#pragma unroll
  for (int j = 0; j < 8; ++j) {
    int n = j*256 + t, p = n >> 3, cg = n & 7;
    unsigned vv[4];
#pragma unroll
    for (int m = 0; m < 4; ++m) {
      int cp = cg*4 + m;
      vv[m] = hrow32[cp*256 + ((p + 2*cp) & 255)];
    }
    hbW[n] = make_uint4(vv[0], vv[1], vv[2], vv[3]);
  }
}

// ---------------- lift: fc0 -> LDS image -> HB (coalesced), DFT-W -> G ----------------
__global__ __launch_bounds__(256) void kl9_lift(const __hip_bfloat16* Xh, const float* Xf,
                                                const float* Wf,
                                                __hip_bfloat16* HB, __hip_bfloat16* GG) {
  __shared__ __align__(16) char smem[32768];
  unsigned* hrow32 = (unsigned*)smem;
  float* pbuf = (float*)smem;
  const int b = blockIdx.x >> 8, x = blockIdx.x & 255;
  const int w = threadIdx.x;
  const int isf32 = (Wf[FLAG_F] != 0.0f);
  float xv = isf32 ? Xf[(size_t)(b*256 + x)*256 + w]
                   : __bfloat162float(Xh[(size_t)(b*256 + x)*256 + w]);
  float gx = x * (1.0f/255.0f), gy = w * (1.0f/255.0f);
#pragma unroll
  for (int cp = 0; cp < 32; ++cp) {
    int c = cp*2;
    float h0 = xv*Wf[FC0_F + c*3]     + gx*Wf[FC0_F + c*3 + 1]
             + gy*Wf[FC0_F + c*3 + 2] + Wf[FC0B_F + c];
    float h1 = xv*Wf[FC0_F + c*3 + 3] + gx*Wf[FC0_F + c*3 + 4]
             + gy*Wf[FC0_F + c*3 + 5] + Wf[FC0B_F + c + 1];
    hrow32[cp*256 + ((w + 2*cp) & 255)] = pk2bf(h0, h1);
  }
  __syncthreads();
  row_store9(HB, hrow32, b, x);
  gstep9(Wf, GG, hrow32, pbuf, b, x);
}

// ---------------- spectral: block=(b,kx); DFT-H + channel mix -> Fo ----------------
__global__ __launch_bounds__(256) void ks9_spec(const float* Wf, const __hip_bfloat16* GG,
    const __hip_bfloat16* w1h, const float* w1f,
    const __hip_bfloat16* w2h, const float* w2f,
    float* Fo, int l) {
  __shared__ float pbufA[6400];
  __shared__ float Fbuf[1536];     // F [i][24] (ky pairs)
  const int b = blockIdx.x / 24, kx = blockIdx.x % 24;
  const int t = threadIdx.x;
  const int isf32 = (Wf[FLAG_F] != 0.0f);
  // A: F[i][ky] = sum_x G[b][x][i][ky] * e^{-i 2pi x kxa/256}
  {
    const int i = t & 63, q = t >> 6;
    float fr[12], fi[12];
#pragma unroll
    for (int k = 0; k < 12; ++k) { fr[k] = 0.0f; fi[k] = 0.0f; }
    for (int j = 0; j < 64; ++j) {
      int x = q*64 + j;                          // wave-uniform
      const uint4* gp = (const uint4*)((const unsigned short*)GG
                        + (size_t)(b*256 + x)*1536 + i*24);
      uint4 u0 = gp[0], u1 = gp[1], u2 = gp[2];
      float cc = Wf[PHH_F + x*48 + 2*kx], ss = Wf[PHH_F + x*48 + 2*kx + 1];
      unsigned uu[12] = {u0.x, u0.y, u0.z, u0.w, u1.x, u1.y, u1.z, u1.w,
                         u2.x, u2.y, u2.z, u2.w};
#pragma unroll
      for (int k = 0; k < 12; ++k) {
        float gr = bfu2f((unsigned short)(uu[k] & 0xFFFFu));
        float gi = bfu2f((unsigned short)(uu[k] >> 16));
        fr[k] += gr*cc + gi*ss;
        fi[k] += gi*cc - gr*ss;
      }
    }
#pragma unroll
    for (int k = 0; k < 12; ++k) {
      pbufA[q*1600 + i*25 + 2*k]     = fr[k];
      pbufA[q*1600 + i*25 + 2*k + 1] = fi[k];
    }
  }
  __syncthreads();
#pragma unroll
  for (int j = 0; j < 6; ++j) {
    int idx = j*256 + t;                         // 1536 = i*24 + m
    int cc = idx / 24, m = idx - cc*24;
    Fbuf[idx] = pbufA[cc*25 + m] + pbufA[1600 + cc*25 + m]
              + pbufA[3200 + cc*25 + m] + pbufA[4800 + cc*25 + m];
  }
  __syncthreads();
  // B: Fo[ky][o] = sum_i F[i][ky] * W[l][i][o][kx][ky]
  {
    const int o = t & 63, q = t >> 6;
    float br[12], bi[12];
#pragma unroll
    for (int k = 0; k < 12; ++k) { br[k] = 0.0f; bi[k] = 0.0f; }
    const int kxe = (kx < 12) ? kx : kx - 12;
    const __hip_bfloat16* wh = (kx < 12) ? w1h : w2h;
    const float*         wfp = (kx < 12) ? w1f : w2f;
    for (int i = q*16; i < q*16 + 16; ++i) {
      size_t widx = ((size_t)((l*64 + i)*64 + o))*288 + (size_t)kxe*24;
      float wr_[12], wi_[12];
      if (isf32) {
        const float* wp = wfp + widx;
#pragma unroll
        for (int k = 0; k < 12; ++k) { wr_[k] = wp[2*k]; wi_[k] = wp[2*k + 1]; }
      } else {
        const uint4* wp = (const uint4*)((const unsigned short*)wh + widx);
        uint4 u0 = wp[0], u1 = wp[1], u2 = wp[2];
        unsigned uu[12] = {u0.x, u0.y, u0.z, u0.w, u1.x, u1.y, u1.z, u1.w,
                           u2.x, u2.y, u2.z, u2.w};
#pragma unroll
        for (int k = 0; k < 12; ++k) {
          wr_[k] = bfu2f((unsigned short)(uu[k] & 0xFFFFu));
          wi_[k] = bfu2f((unsigned short)(uu[k] >> 16));
        }
      }
      const float* Fp = Fbuf + i*24;
#pragma unroll
      for (int k = 0; k < 12; ++k) {
        float Fr = Fp[2*k], Fi = Fp[2*k + 1];
        br[k] += Fr*wr_[k] - Fi*wi_[k];
        bi[k] += Fr*wi_[k] + Fi*wr_[k];
      }
    }
#pragma unroll
    for (int k = 0; k < 12; ++k) {
      pbufA[q*1536 + k*128 + o*2]     = br[k];
      pbufA[q*1536 + k*128 + o*2 + 1] = bi[k];
    }
  }
  __syncthreads();
#pragma unroll
  for (int j = 0; j < 6; ++j) {
    int n = j*256 + t;                           // 1536 = ky*128 + o*2 + p
    int ky = n >> 7, r = n & 127;
    Fo[((size_t)(b*12 + ky)*24 + kx)*128 + r] =
        pbufA[n] + pbufA[1536 + n] + pbufA[3072 + n] + pbufA[4608 + n];
  }
}

// ---------------- ginv: inverse-H Fo -> g2 rows (OVERWRITES GG region) ----------------
// g2 row (b,x): u32[ky*64 + o] = packed (re, im) bf16
__global__ __launch_bounds__(256) void kg9_ginv(const float* Wf, const float* Fo,
                                                __hip_bfloat16* GG) {
  const int blk = blockIdx.x;            // 768 = b*96 + ky*8 + xg
  const int b = blk / 96, r = blk % 96, ky = r / 8, xg = r % 8;
  const int t = threadIdx.x;
  const int o = t & 63, xi = t >> 6;
  // load this (b,ky,o)'s 24 Fo complex values
  const float2* Fop = (const float2*)(Fo + (size_t)(b*12 + ky)*24*128) + o;
  float fr[24], fi[24];
#pragma unroll
  for (int kx = 0; kx < 24; ++kx) {
    float2 f = Fop[kx*64];
    fr[kx] = f.x; fi[kx] = f.y;
  }
#pragma unroll
  for (int m = 0; m < 8; ++m) {
    int x = xg*32 + xi + 4*m;            // wave-uniform (xi = wave id)
    const float* phx = Wf + PHH_F + x*48;
    float gr = 0.0f, gi = 0.0f;
#pragma unroll
    for (int kx = 0; kx < 24; ++kx) {
      float cc = phx[2*kx], ss = phx[2*kx + 1];
      gr += fr[kx]*cc - fi[kx]*ss;
      gi += fr[kx]*ss + fi[kx]*cc;
    }
    unsigned* GGrow = (unsigned*)((unsigned short*)GG + (size_t)(b*256 + x)*1536);
    GGrow[ky*64 + o] = pk2bf(gr, gi);
  }
}

// ---------------- layer: inv-W + pointwise + GELU (+ next DFT-W) ----------------
__global__ __launch_bounds__(256, 4) void ky9_layer(const float* Wf,
                                                    __hip_bfloat16* HB,
                                                    __hip_bfloat16* GG,
                                                    int l, int last) {
  __shared__ __align__(16) char smem[38912];     // hrow32 32KB (alias pbuf) + gbuf 6KB
  unsigned* hrow32 = (unsigned*)smem;
  float* pbuf = (float*)smem;
  float* gbuf = (float*)(smem + 32768);          // [ky][o][2] 1536 floats
  const int b = blockIdx.x >> 8, x = blockIdx.x & 255;
  const int t = threadIdx.x;
  const int w = t;
  // g2 row -> gbuf (coalesced u32 loads, unpack to f32 LDS)
  {
    const unsigned* g2row = (const unsigned*)((const unsigned short*)GG
                            + (size_t)(b*256 + x)*1536);
#pragma unroll
    for (int j = 0; j < 3; ++j) {
      int n = j*256 + t;                         // 768 = ky*64 + o
      unsigned u = g2row[n];
      int ky = n >> 6, o = n & 63;
      gbuf[ky*128 + o*2]     = bfu2f((unsigned short)(u & 0xFFFFu));
      gbuf[ky*128 + o*2 + 1] = bfu2f((unsigned short)(u >> 16));
    }
  }
  // per-lane h row (each lane owns its pixel's full 128B line)
  unsigned hp[32];
  {
    const uint4* hbR = (const uint4*)(HB + (size_t)(b*256 + x)*16384) + w*8;
#pragma unroll
    for (int j = 0; j < 8; ++j) {
      uint4 v = hbR[j];
      hp[j*4] = v.x; hp[j*4+1] = v.y; hp[j*4+2] = v.z; hp[j*4+3] = v.w;
    }
  }
  __syncthreads();                               // gbuf ready
  float pc[11], ps[11];
#pragma unroll
  for (int k = 0; k < 11; ++k) {
    int idx = (w*(k + 1)) & 255;
    float a = idx * (1.0f/128.0f);
    pc[k] = 2.0f * cospif(a);
    ps[k] = 2.0f * sinpif(a);
  }
  const float* pw  = Wf + PWF_F + l*4096;
  const float* pwb = Wf + PWB_F + l*64;
#pragma unroll 1
  for (int half = 0; half < 2; ++half) {
    const int o0 = half*32;
    float acc[32];
#pragma unroll
    for (int oo = 0; oo < 32; ++oo) acc[oo] = gbuf[(o0 + oo)*2];
#pragma unroll
    for (int k = 1; k < 12; ++k) {
#pragma unroll
      for (int oo = 0; oo < 32; ++oo)
        acc[oo] += gbuf[k*128 + (o0 + oo)*2] * pc[k-1]
                 - gbuf[k*128 + (o0 + oo)*2 + 1] * ps[k-1];
    }
#pragma unroll
    for (int oo = 0; oo < 32; ++oo) acc[oo] = pwb[o0 + oo] + acc[oo] * (1.0f/65536.0f);
    for (int i = 0; i < 64; ++i) {
      float hv = hunp9(hp, i);
#pragma unroll
      for (int oo = 0; oo < 32; ++oo) acc[oo] += hv * pw[i*64 + o0 + oo];
    }
#pragma unroll
    for (int m = 0; m < 16; ++m) {
      int oo = m*2;
      float v0 = acc[oo], v1 = acc[oo + 1];
      if (!last) { v0 = gelu9(v0); v1 = gelu9(v1); }
      int cp = half*16 + m;
      hrow32[cp*256 + ((w + 2*cp) & 255)] = pk2bf(v0, v1);   // owner-only write
    }
  }
  __syncthreads();                               // image complete
  row_store9(HB, hrow32, b, x);
  if (!last) gstep9(Wf, GG, hrow32, pbuf, b, x);
}

// ---------------- head: fc1 + GELU + fc2 -> out ----------------
__global__ __launch_bounds__(256, 4) void kh9_head(const float* Wf,
                                                   const __hip_bfloat16* HB,
                                                   __hip_bfloat16* outH, float* outF) {
  const int b = blockIdx.x >> 8, x = blockIdx.x & 255;
  const int w = threadIdx.x;
  const int isf32 = (Wf[FLAG_F] != 0.0f);
  unsigned hp[32];
  {
    const uint4* hbR = (const uint4*)(HB + (size_t)(b*256 + x)*16384) + w*8;
#pragma unroll
    for (int j = 0; j < 8; ++j) {
      uint4 v = hbR[j];
      hp[j*4] = v.x; hp[j*4+1] = v.y; hp[j*4+2] = v.z; hp[j*4+3] = v.w;
    }
  }
  float total = Wf[FC2B_F];
#pragma unroll 1
  for (int half = 0; half < 2; ++half) {
    float acc[64];
#pragma unroll
    for (int o = 0; o < 64; ++o) acc[o] = Wf[FC1B_F + half*64 + o];
    for (int i = 0; i < 64; ++i) {
      float hv = hunp9(hp, i);
#pragma unroll
      for (int o = 0; o < 64; ++o) acc[o] += hv * Wf[FC1T_F + i*128 + half*64 + o];
    }
#pragma unroll
    for (int o = 0; o < 64; ++o)
      total += gelu9(acc[o]) * Wf[FC2_F + half*64 + o];
  }
  size_t idx = (size_t)(b*256 + x)*256 + w;
  if (isf32) outF[idx] = total;
  else       outH[idx] = __float2bfloat16(total);
}

// ---------------- launcher ----------------
extern "C" void kernel_launch(void* const* d_in, const int* in_sizes, int n_in,
                              void* d_out, int out_size, void* d_ws, size_t ws_size,
                              hipStream_t stream) {
  (void)out_size;
  __hip_bfloat16* outH = (__hip_bfloat16*)d_out;
  float*          outF = (float*)d_out;
  float*          Wf   = (float*)d_ws;
  __hip_bfloat16* HB   = (__hip_bfloat16*)d_ws + HB_OFF_U;
  __hip_bfloat16* GG   = (__hip_bfloat16*)d_ws + GG_OFF_U;
  float*          Fo   = (float*)d_ws + FO_OFF_F;

  static const int EXP_SZ[11] = {524288, 192, 64, 4718592, 4718592,
                                 16384, 256, 8192, 128, 128, 1};
  if (n_in != 11) { kf9_fill<<<2048, 256, 0, stream>>>(outH, 27648.0f); return; }
  for (int i = 0; i < 11; ++i) {
    if (in_sizes[i] != EXP_SZ[i]) {
      kf9_fill<<<2048, 256, 0, stream>>>(outH, 28672.0f + 256.0f * (float)i);
      return;
    }
  }
  if (ws_size < (size_t)WS_NEED) {
    int q = (int)(ws_size >> 25); if (q > 31) q = 31;
    kf9_fill<<<2048, 256, 0, stream>>>(outH, 4096.0f + 32.0f * (float)q);
    return;
  }

  kd9_detect<<<1, 64, 0, stream>>>((const unsigned short*)d_in[0], Wf);
  kt9_tables<<<64, 256, 0, stream>>>(
      (const __hip_bfloat16*)d_in[1], (const float*)d_in[1],
      (const __hip_bfloat16*)d_in[2], (const float*)d_in[2],
      (const __hip_bfloat16*)d_in[5], (const float*)d_in[5],
      (const __hip_bfloat16*)d_in[6], (const float*)d_in[6],
      (const __hip_bfloat16*)d_in[7], (const float*)d_in[7],
      (const __hip_bfloat16*)d_in[8], (const float*)d_in[8],
      (const __hip_bfloat16*)d_in[9], (const float*)d_in[9],
      (const __hip_bfloat16*)d_in[10], (const float*)d_in[10],
      Wf);
  kl9_lift<<<2048, 256, 0, stream>>>((const __hip_bfloat16*)d_in[0],
                                     (const float*)d_in[0], Wf, HB, GG);
  for (int l = 0; l < 4; ++l) {
    ks9_spec<<<192, 256, 0, stream>>>(Wf, GG,
        (const __hip_bfloat16*)d_in[3], (const float*)d_in[3],
        (const __hip_bfloat16*)d_in[4], (const float*)d_in[4],
        Fo, l);
    kg9_ginv<<<768, 256, 0, stream>>>(Wf, Fo, GG);
    ky9_layer<<<2048, 256, 0, stream>>>(Wf, HB, GG, l, (l == 3) ? 1 : 0);
  }
  kh9_head<<<2048, 256, 0, stream>>>(Wf, HB, outH, outF);
}

// Round 10
// 1836.215 us; speedup vs baseline: 1.8576x; 1.8345x over previous
//
#include <hip/hip_runtime.h>
#include <hip/hip_bf16.h>

// ---------------- workspace layout v10 (total 74,842,112 bytes) ----------------
// float indices into (float*)d_ws:
#define FC0_F   0        // fc0_w [64][3]
#define FC0B_F  192      // fc0_b [64]
#define PWF_F   256      // pw_w transposed [4][i][o] (16384)
#define PWB_F   16640    // pw_b [4][64]
#define FC1T_F  16896    // fc1_w transposed [64 i][128 f] (8192)
#define FC1B_F  25088    // fc1_b [128]
#define FC2_F   25216    // fc2_w [128]
#define FC2B_F  25344    // fc2_b [1]
#define PHW_F   25408    // phW [256 w][12 ky][2] (6144)
#define PHH_F   31552    // phH [256 x][24 kx][2] (12288) -> end 43840
#define FLAG_F  44032    // 1.0 => inputs f32
// bf16 element indices into (__hip_bfloat16*)d_ws:
#define HB_OFF_U  131072     // h [8][256][256][64]  (33554432 elems)
#define GG_OFF_U  33685504   // G / g2 shared region: [8][256] rows x 1536 bf16
// float index for Fo:
#define FO_OFF_F  18415616   // Fo [8][12][24][64][2] f32 (294912)
#define WS_NEED   74842112
#define NTAB 43840

union FU10 { float f; unsigned u; };
__device__ __forceinline__ float bfu2f(unsigned short u) { FU10 v; v.u = ((unsigned)u) << 16; return v.f; }
__device__ __forceinline__ unsigned short f2bfu(float f) {
  FU10 v; v.f = f; unsigned b = v.u;
  return (unsigned short)((b + 0x7FFFu + ((b >> 16) & 1u)) >> 16);   // RNE
}
__device__ __forceinline__ float hunp10(const unsigned* hp, int i) {
  unsigned u = hp[i >> 1];
  return bfu2f((unsigned short)((i & 1) ? (u >> 16) : (u & 0xFFFFu)));
}
__device__ __forceinline__ unsigned pk2bf(float a, float b) {
  return (unsigned)f2bfu(a) | ((unsigned)f2bfu(b) << 16);
}
__device__ __forceinline__ float gelu10(float v) {
  return 0.5f * v * (1.0f + erff(v * 0.7071067811865475f));
}
__device__ __forceinline__ float rdw10(const __hip_bfloat16* h, const float* f,
                                       long i, int isf32) {
  return isf32 ? f[i] : __bfloat162float(h[i]);
}

// ---------------- fill output with a code (guards only) ----------------
__global__ __launch_bounds__(256) void kf10_fill(__hip_bfloat16* outH, float code) {
  outH[(size_t)blockIdx.x * 256 + threadIdx.x] = __float2bfloat16(code);
}

// ---------------- dtype detect on X ----------------
__global__ __launch_bounds__(64) void kd10_detect(const unsigned short* Xh, float* Wf) {
  if (threadIdx.x == 0 && blockIdx.x == 0) {
    int ok = 1;
    for (int k = 0; k < 128; ++k) {
      unsigned short u = Xh[2 * k];
      unsigned e = (u >> 7) & 0xFF;
      if (!(u == 0 || (e >= 0x60 && e <= 0x88))) ok = 0;
    }
    Wf[FLAG_F] = ok ? 0.0f : 1.0f;
  }
}

// ---------------- tables ----------------
__global__ __launch_bounds__(256) void kt10_tables(
    const __hip_bfloat16* f0h, const float* f0f,
    const __hip_bfloat16* f0bh, const float* f0bf,
    const __hip_bfloat16* pwh, const float* pwf,
    const __hip_bfloat16* pwbh, const float* pwbf,
    const __hip_bfloat16* f1h, const float* f1f,
    const __hip_bfloat16* f1bh, const float* f1bf,
    const __hip_bfloat16* f2h, const float* f2f,
    const __hip_bfloat16* f2bh, const float* f2bf,
    float* Wf) {
  const int isf32 = (Wf[FLAG_F] != 0.0f);
  const int stride = gridDim.x * blockDim.x;
  for (int n0 = blockIdx.x * blockDim.x + threadIdx.x; n0 < NTAB; n0 += stride) {
    int n = n0;
    if (n < 192) { Wf[FC0_F + n] = rdw10(f0h, f0f, n, isf32); continue; }
    n -= 192;
    if (n < 64)  { Wf[FC0B_F + n] = rdw10(f0bh, f0bf, n, isf32); continue; }
    n -= 64;
    if (n < 16384) { int l = n >> 12, i = (n >> 6) & 63, o = n & 63;
      Wf[PWF_F + n] = rdw10(pwh, pwf, (l*64 + o)*64 + i, isf32); continue; }
    n -= 16384;
    if (n < 256) { Wf[PWB_F + n] = rdw10(pwbh, pwbf, n, isf32); continue; }
    n -= 256;
    if (n < 8192) { int i = n >> 7, f = n & 127;
      Wf[FC1T_F + n] = rdw10(f1h, f1f, f*64 + i, isf32); continue; }
    n -= 8192;
    if (n < 128) { Wf[FC1B_F + n] = rdw10(f1bh, f1bf, n, isf32); continue; }
    n -= 128;
    if (n < 128) { Wf[FC2_F + n] = rdw10(f2h, f2f, n, isf32); continue; }
    n -= 128;
    if (n < 1)   { Wf[FC2B_F + n] = rdw10(f2bh, f2bf, 0, isf32); continue; }
    n -= 1;
    if (n < 6144) { int w = n / 24, r = n % 24, ky = r >> 1, part = r & 1;
      int idx = (w * ky) & 255; float a = idx * (1.0f/128.0f);
      Wf[PHW_F + n] = part ? sinpif(a) : cospif(a); continue; }
    n -= 6144;
    { int x = n / 48, r = n % 48, kx = r >> 1, part = r & 1;
      int kxa = (kx < 12) ? kx : kx + 232;          // 244..255 = negative H rows
      int idx = (x * kxa) & 255; float a = idx * (1.0f/128.0f);
      Wf[PHH_F + n] = part ? sinpif(a) : cospif(a); }
  }
}

// hrow32 packed-pair swizzled image of the (b,x) row:
//   word for (pixel p, channel-pair cp) at hrow32[cp*256 + ((p + 2*cp) & 255)]
// ---------------- forward DFT along W of the LDS row -> G rows in GG ----------------
__device__ void gstep10(const float* Wf, __hip_bfloat16* GG,
                        unsigned* hrow32, float* pbuf, int b, int x) {
  const int t = threadIdx.x;
  const int c = t & 63, q = t >> 6;
  const int cp = c >> 1, hi = c & 1;
  float aR[12], aI[12];
#pragma unroll
  for (int k = 0; k < 12; ++k) { aR[k] = 0.0f; aI[k] = 0.0f; }
  for (int j = 0; j < 64; ++j) {
    int w = q*64 + j;                            // wave-uniform
    unsigned u = hrow32[cp*256 + ((w + 2*cp) & 255)];
    float hv = bfu2f((unsigned short)(hi ? (u >> 16) : (u & 0xFFFFu)));
    const float* ph = Wf + PHW_F + w*24;
#pragma unroll
    for (int k = 0; k < 12; ++k) {
      aR[k] += hv * ph[2*k];
      aI[k] -= hv * ph[2*k + 1];
    }
  }
  __syncthreads();                               // hrow reads done; pbuf may overwrite
#pragma unroll
  for (int k = 0; k < 12; ++k) {
    pbuf[q*1600 + c*25 + 2*k]     = aR[k];
    pbuf[q*1600 + c*25 + 2*k + 1] = aI[k];
  }
  __syncthreads();
  unsigned* Grow = (unsigned*)((unsigned short*)GG + (size_t)(b*256 + x)*1536);
#pragma unroll
  for (int j = 0; j < 3; ++j) {
    int p = j*256 + t;                 // pair index; elem 2p = cc*24 + m  ([i][ky][2] row)
    int cc = p / 12;
    int m0 = 2*p - cc*24;
    float s0 = pbuf[cc*25 + m0]     + pbuf[1600 + cc*25 + m0]
             + pbuf[3200 + cc*25 + m0]     + pbuf[4800 + cc*25 + m0];
    float s1 = pbuf[cc*25 + m0 + 1] + pbuf[1600 + cc*25 + m0 + 1]
             + pbuf[3200 + cc*25 + m0 + 1] + pbuf[4800 + cc*25 + m0 + 1];
    Grow[p] = pk2bf(s0, s1);
  }
}

// coalesced LDS image -> HB(row)
__device__ __forceinline__ void row_store10(__hip_bfloat16* HB, const unsigned* hrow32,
                                            int b, int x) {
  uint4* hbW = (uint4*)(HB + (size_t)(b*256 + x)*16384);
  const int t = threadIdx.x;
#pragma unroll
  for (int j = 0; j < 8; ++j) {
    int n = j*256 + t, p = n >> 3, cg = n & 7;
    unsigned vv[4];
#pragma unroll
    for (int m = 0; m < 4; ++m) {
      int cp = cg*4 + m;
      vv[m] = hrow32[cp*256 + ((p + 2*cp) & 255)];
    }
    hbW[n] = make_uint4(vv[0], vv[1], vv[2], vv[3]);
  }
}

// ---------------- lift: fc0 -> LDS image -> HB (coalesced), DFT-W -> G ----------------
__global__ __launch_bounds__(256) void kl10_lift(const __hip_bfloat16* Xh, const float* Xf,
                                                 const float* Wf,
                                                 __hip_bfloat16* HB, __hip_bfloat16* GG) {
  __shared__ __align__(16) char smem[32768];
  unsigned* hrow32 = (unsigned*)smem;
  float* pbuf = (float*)smem;
  const int b = blockIdx.x >> 8, x = blockIdx.x & 255;
  const int w = threadIdx.x;
  const int isf32 = (Wf[FLAG_F] != 0.0f);
  float xv = isf32 ? Xf[(size_t)(b*256 + x)*256 + w]
                   : __bfloat162float(Xh[(size_t)(b*256 + x)*256 + w]);
  float gx = x * (1.0f/255.0f), gy = w * (1.0f/255.0f);
#pragma unroll
  for (int cp = 0; cp < 32; ++cp) {
    int c = cp*2;
    float h0 = xv*Wf[FC0_F + c*3]     + gx*Wf[FC0_F + c*3 + 1]
             + gy*Wf[FC0_F + c*3 + 2] + Wf[FC0B_F + c];
    float h1 = xv*Wf[FC0_F + c*3 + 3] + gx*Wf[FC0_F + c*3 + 4]
             + gy*Wf[FC0_F + c*3 + 5] + Wf[FC0B_F + c + 1];
    hrow32[cp*256 + ((w + 2*cp) & 255)] = pk2bf(h0, h1);
  }
  __syncthreads();
  row_store10(HB, hrow32, b, x);
  gstep10(Wf, GG, hrow32, pbuf, b, x);
}

// ---------------- spectral: block=(b,kx); DFT-H + channel mix -> Fo ----------------
__global__ __launch_bounds__(256) void ks10_spec(const float* Wf, const __hip_bfloat16* GG,
    const __hip_bfloat16* w1h, const float* w1f,
    const __hip_bfloat16* w2h, const float* w2f,
    float* Fo, int l) {
  __shared__ float pbufA[6400];
  __shared__ float Fbuf[1536];     // F [i][24] (ky pairs)
  const int b = blockIdx.x / 24, kx = blockIdx.x % 24;
  const int t = threadIdx.x;
  const int isf32 = (Wf[FLAG_F] != 0.0f);
  // A: F[i][ky] = sum_x G[b][x][i][ky] * e^{-i 2pi x kxa/256}
  {
    const int i = t & 63, q = t >> 6;
    float fr[12], fi[12];
#pragma unroll
    for (int k = 0; k < 12; ++k) { fr[k] = 0.0f; fi[k] = 0.0f; }
    for (int j = 0; j < 64; ++j) {
      int x = q*64 + j;                          // wave-uniform
      const uint4* gp = (const uint4*)((const unsigned short*)GG
                        + (size_t)(b*256 + x)*1536 + i*24);
      uint4 u0 = gp[0], u1 = gp[1], u2 = gp[2];
      float cc = Wf[PHH_F + x*48 + 2*kx], ss = Wf[PHH_F + x*48 + 2*kx + 1];
      unsigned uu[12] = {u0.x, u0.y, u0.z, u0.w, u1.x, u1.y, u1.z, u1.w,
                         u2.x, u2.y, u2.z, u2.w};
#pragma unroll
      for (int k = 0; k < 12; ++k) {
        float gr = bfu2f((unsigned short)(uu[k] & 0xFFFFu));
        float gi = bfu2f((unsigned short)(uu[k] >> 16));
        fr[k] += gr*cc + gi*ss;
        fi[k] += gi*cc - gr*ss;
      }
    }
#pragma unroll
    for (int k = 0; k < 12; ++k) {
      pbufA[q*1600 + i*25 + 2*k]     = fr[k];
      pbufA[q*1600 + i*25 + 2*k + 1] = fi[k];
    }
  }
  __syncthreads();
#pragma unroll
  for (int j = 0; j < 6; ++j) {
    int idx = j*256 + t;                         // 1536 = i*24 + m
    int cc = idx / 24, m = idx - cc*24;
    Fbuf[idx] = pbufA[cc*25 + m] + pbufA[1600 + cc*25 + m]
              + pbufA[3200 + cc*25 + m] + pbufA[4800 + cc*25 + m];
  }
  __syncthreads();
  // B: Fo[ky][o] = sum_i F[i][ky] * W[l][i][o][kx][ky]
  {
    const int o = t & 63, q = t >> 6;
    float br[12], bi[12];
#pragma unroll
    for (int k = 0; k < 12; ++k) { br[k] = 0.0f; bi[k] = 0.0f; }
    const int kxe = (kx < 12) ? kx : kx - 12;
    const __hip_bfloat16* wh = (kx < 12) ? w1h : w2h;
    const float*         wfp = (kx < 12) ? w1f : w2f;
    for (int i = q*16; i < q*16 + 16; ++i) {
      size_t widx = ((size_t)((l*64 + i)*64 + o))*288 + (size_t)kxe*24;
      float wr_[12], wi_[12];
      if (isf32) {
        const float* wp = wfp + widx;
#pragma unroll
        for (int k = 0; k < 12; ++k) { wr_[k] = wp[2*k]; wi_[k] = wp[2*k + 1]; }
      } else {
        const uint4* wp = (const uint4*)((const unsigned short*)wh + widx);
        uint4 u0 = wp[0], u1 = wp[1], u2 = wp[2];
        unsigned uu[12] = {u0.x, u0.y, u0.z, u0.w, u1.x, u1.y, u1.z, u1.w,
                           u2.x, u2.y, u2.z, u2.w};
#pragma unroll
        for (int k = 0; k < 12; ++k) {
          wr_[k] = bfu2f((unsigned short)(uu[k] & 0xFFFFu));
          wi_[k] = bfu2f((unsigned short)(uu[k] >> 16));
        }
      }
      const float* Fp = Fbuf + i*24;
#pragma unroll
      for (int k = 0; k < 12; ++k) {
        float Fr = Fp[2*k], Fi = Fp[2*k + 1];
        br[k] += Fr*wr_[k] - Fi*wi_[k];
        bi[k] += Fr*wi_[k] + Fi*wr_[k];
      }
    }
#pragma unroll
    for (int k = 0; k < 12; ++k) {
      pbufA[q*1536 + k*128 + o*2]     = br[k];
      pbufA[q*1536 + k*128 + o*2 + 1] = bi[k];
    }
  }
  __syncthreads();
#pragma unroll
  for (int j = 0; j < 6; ++j) {
    int n = j*256 + t;                           // 1536 = ky*128 + o*2 + p
    int ky = n >> 7, r = n & 127;
    Fo[((size_t)(b*12 + ky)*24 + kx)*128 + r] =
        pbufA[n] + pbufA[1536 + n] + pbufA[3072 + n] + pbufA[4608 + n];
  }
}

// ---------------- ginv: inverse-H Fo -> g2 rows (OVERWRITES GG region) ----------------
// g2 row (b,x): u32[ky*64 + o] = packed (re, im) bf16
__global__ __launch_bounds__(256) void kg10_ginv(const float* Wf, const float* Fo,
                                                 __hip_bfloat16* GG) {
  const int blk = blockIdx.x;            // 768 = b*96 + ky*8 + xg
  const int b = blk / 96, r = blk % 96, ky = r / 8, xg = r % 8;
  const int t = threadIdx.x;
  const int o = t & 63, xi = t >> 6;
  const float2* Fop = (const float2*)(Fo + (size_t)(b*12 + ky)*24*128) + o;
  float fr[24], fi[24];
#pragma unroll
  for (int kx = 0; kx < 24; ++kx) {
    float2 f = Fop[kx*64];
    fr[kx] = f.x; fi[kx] = f.y;
  }
#pragma unroll
  for (int m = 0; m < 8; ++m) {
    int x = xg*32 + xi + 4*m;            // wave-uniform (xi = wave id)
    const float* phx = Wf + PHH_F + x*48;
    float gr = 0.0f, gi = 0.0f;
#pragma unroll
    for (int kx = 0; kx < 24; ++kx) {
      float cc = phx[2*kx], ss = phx[2*kx + 1];
      gr += fr[kx]*cc - fi[kx]*ss;
      gi += fr[kx]*ss + fi[kx]*cc;
    }
    unsigned* GGrow = (unsigned*)((unsigned short*)GG + (size_t)(b*256 + x)*1536);
    GGrow[ky*64 + o] = pk2bf(gr, gi);
  }
}

// ---------------- layer: inv-W + pointwise + GELU (+ next DFT-W) ----------------
// NOTE: no min-waves bound — R7-R9's (256,4) forced 64 VGPRs and scratch-spilled
// ~680 MB/dispatch (WRITE_SIZE 448 MB vs 70 MB logical). Let the allocator pick.
__global__ __launch_bounds__(256) void ky10_layer(const float* Wf,
                                                  __hip_bfloat16* HB,
                                                  __hip_bfloat16* GG,
                                                  int l, int last) {
  __shared__ __align__(16) char smem[38912];     // hrow32 32KB (alias pbuf) + gbuf 6KB
  unsigned* hrow32 = (unsigned*)smem;
  float* pbuf = (float*)smem;
  float* gbuf = (float*)(smem + 32768);          // [ky][o][2] 1536 floats
  const int b = blockIdx.x >> 8, x = blockIdx.x & 255;
  const int t = threadIdx.x;
  const int w = t;
  // g2 row -> gbuf (coalesced u32 loads, unpack to f32 LDS)
  {
    const unsigned* g2row = (const unsigned*)((const unsigned short*)GG
                            + (size_t)(b*256 + x)*1536);
#pragma unroll
    for (int j = 0; j < 3; ++j) {
      int n = j*256 + t;                         // 768 = ky*64 + o
      unsigned u = g2row[n];
      int ky = n >> 6, o = n & 63;
      gbuf[ky*128 + o*2]     = bfu2f((unsigned short)(u & 0xFFFFu));
      gbuf[ky*128 + o*2 + 1] = bfu2f((unsigned short)(u >> 16));
    }
  }
  // per-lane h row (each lane owns its pixel's full 128B line)
  unsigned hp[32];
  {
    const uint4* hbR = (const uint4*)(HB + (size_t)(b*256 + x)*16384) + w*8;
#pragma unroll
    for (int j = 0; j < 8; ++j) {
      uint4 v = hbR[j];
      hp[j*4] = v.x; hp[j*4+1] = v.y; hp[j*4+2] = v.z; hp[j*4+3] = v.w;
    }
  }
  __syncthreads();                               // gbuf ready
  float pc[11], ps[11];
#pragma unroll
  for (int k = 0; k < 11; ++k) {
    int idx = (w*(k + 1)) & 255;
    float a = idx * (1.0f/128.0f);
    pc[k] = 2.0f * cospif(a);
    ps[k] = 2.0f * sinpif(a);
  }
  const float* pw  = Wf + PWF_F + l*4096;
  const float* pwb = Wf + PWB_F + l*64;
#pragma unroll 1
  for (int half = 0; half < 2; ++half) {
    const int o0 = half*32;
    float acc[32];
#pragma unroll
    for (int oo = 0; oo < 32; ++oo) acc[oo] = gbuf[(o0 + oo)*2];
#pragma unroll
    for (int k = 1; k < 12; ++k) {
#pragma unroll
      for (int oo = 0; oo < 32; ++oo)
        acc[oo] += gbuf[k*128 + (o0 + oo)*2] * pc[k-1]
                 - gbuf[k*128 + (o0 + oo)*2 + 1] * ps[k-1];
    }
#pragma unroll
    for (int oo = 0; oo < 32; ++oo) acc[oo] = pwb[o0 + oo] + acc[oo] * (1.0f/65536.0f);
    for (int i = 0; i < 64; ++i) {
      float hv = hunp10(hp, i);
#pragma unroll
      for (int oo = 0; oo < 32; ++oo) acc[oo] += hv * pw[i*64 + o0 + oo];
    }
#pragma unroll
    for (int m = 0; m < 16; ++m) {
      int oo = m*2;
      float v0 = acc[oo], v1 = acc[oo + 1];
      if (!last) { v0 = gelu10(v0); v1 = gelu10(v1); }
      int cp = half*16 + m;
      hrow32[cp*256 + ((w + 2*cp) & 255)] = pk2bf(v0, v1);   // owner-only write
    }
  }
  __syncthreads();                               // image complete
  row_store10(HB, hrow32, b, x);
  if (!last) gstep10(Wf, GG, hrow32, pbuf, b, x);
}

// ---------------- head: fc1 + GELU + fc2 -> out (no min-waves bound: avoid spills) ----------------
__global__ __launch_bounds__(256) void kh10_head(const float* Wf,
                                                 const __hip_bfloat16* HB,
                                                 __hip_bfloat16* outH, float* outF) {
  const int b = blockIdx.x >> 8, x = blockIdx.x & 255;
  const int w = threadIdx.x;
  const int isf32 = (Wf[FLAG_F] != 0.0f);
  unsigned hp[32];
  {
    const uint4* hbR = (const uint4*)(HB + (size_t)(b*256 + x)*16384) + w*8;
#pragma unroll
    for (int j = 0; j < 8; ++j) {
      uint4 v = hbR[j];
      hp[j*4] = v.x; hp[j*4+1] = v.y; hp[j*4+2] = v.z; hp[j*4+3] = v.w;
    }
  }
  float total = Wf[FC2B_F];
#pragma unroll 1
  for (int half = 0; half < 2; ++half) {
    float acc[64];
#pragma unroll
    for (int o = 0; o < 64; ++o) acc[o] = Wf[FC1B_F + half*64 + o];
    for (int i = 0; i < 64; ++i) {
      float hv = hunp10(hp, i);
#pragma unroll
      for (int o = 0; o < 64; ++o) acc[o] += hv * Wf[FC1T_F + i*128 + half*64 + o];
    }
#pragma unroll
    for (int o = 0; o < 64; ++o)
      total += gelu10(acc[o]) * Wf[FC2_F + half*64 + o];
  }
  size_t idx = (size_t)(b*256 + x)*256 + w;
  if (isf32) outF[idx] = total;
  else       outH[idx] = __float2bfloat16(total);
}

// ---------------- launcher ----------------
extern "C" void kernel_launch(void* const* d_in, const int* in_sizes, int n_in,
                              void* d_out, int out_size, void* d_ws, size_t ws_size,
                              hipStream_t stream) {
  (void)out_size;
  __hip_bfloat16* outH = (__hip_bfloat16*)d_out;
  float*          outF = (float*)d_out;
  float*          Wf   = (float*)d_ws;
  __hip_bfloat16* HB   = (__hip_bfloat16*)d_ws + HB_OFF_U;
  __hip_bfloat16* GG   = (__hip_bfloat16*)d_ws + GG_OFF_U;
  float*          Fo   = (float*)d_ws + FO_OFF_F;

  static const int EXP_SZ[11] = {524288, 192, 64, 4718592, 4718592,
                                 16384, 256, 8192, 128, 128, 1};
  if (n_in != 11) { kf10_fill<<<2048, 256, 0, stream>>>(outH, 27648.0f); return; }
  for (int i = 0; i < 11; ++i) {
    if (in_sizes[i] != EXP_SZ[i]) {
      kf10_fill<<<2048, 256, 0, stream>>>(outH, 28672.0f + 256.0f * (float)i);
      return;
    }
  }
  if (ws_size < (size_t)WS_NEED) {
    int q = (int)(ws_size >> 25); if (q > 31) q = 31;
    kf10_fill<<<2048, 256, 0, stream>>>(outH, 4096.0f + 32.0f * (float)q);
    return;
  }

  kd10_detect<<<1, 64, 0, stream>>>((const unsigned short*)d_in[0], Wf);
  kt10_tables<<<64, 256, 0, stream>>>(
      (const __hip_bfloat16*)d_in[1], (const float*)d_in[1],
      (const __hip_bfloat16*)d_in[2], (const float*)d_in[2],
      (const __hip_bfloat16*)d_in[5], (const float*)d_in[5],
      (const __hip_bfloat16*)d_in[6], (const float*)d_in[6],
      (const __hip_bfloat16*)d_in[7], (const float*)d_in[7],
      (const __hip_bfloat16*)d_in[8], (const float*)d_in[8],
      (const __hip_bfloat16*)d_in[9], (const float*)d_in[9],
      (const __hip_bfloat16*)d_in[10], (const float*)d_in[10],
      Wf);
  kl10_lift<<<2048, 256, 0, stream>>>((const __hip_bfloat16*)d_in[0],
                                      (const float*)d_in[0], Wf, HB, GG);
  for (int l = 0; l < 4; ++l) {
    ks10_spec<<<192, 256, 0, stream>>>(Wf, GG,
        (const __hip_bfloat16*)d_in[3], (const float*)d_in[3],
        (const __hip_bfloat16*)d_in[4], (const float*)d_in[4],
        Fo, l);
    kg10_ginv<<<768, 256, 0, stream>>>(Wf, Fo, GG);
    ky10_layer<<<2048, 256, 0, stream>>>(Wf, HB, GG, l, (l == 3) ? 1 : 0);
  }
  kh10_head<<<2048, 256, 0, stream>>>(Wf, HB, outH, outF);
}